// Round 13
// baseline (295.643 us; speedup 1.0000x reference)
//
#include <hip/hip_runtime.h>
#include <hip/hip_bf16.h>

#define B_   128
#define T_   512
#define H_   512
#define V_   16
#define OUT_ 64
#define DH_  1024
#define NCH  8     // t-chunks per batch for the fused epilogue

// hbuf layout: [b][T_][DH_]  (b-major)

// scan LDS: tab float4[V][H] (128K) + tsA float2[T] (4K) + vpk uchar[T] (512B)
#define TAB_BYTES (V_*H_*16)
#define TSA_BYTES (T_*8)
#define VPK_BYTES (T_)
#define SCAN_LDS  (TAB_BYTES + TSA_BYTES + VPK_BYTES)   // 135,680 B

#define LOG2E 1.4426950408889634f

__device__ __forceinline__ float bf2f_lo(unsigned int u) {
    union { unsigned int i; float f; } x; x.i = u << 16; return x.f;
}
__device__ __forceinline__ float bf2f_hi(unsigned int u) {
    union { unsigned int i; float f; } x; x.i = u & 0xffff0000u; return x.f;
}

__device__ __forceinline__ float dot16(const uint4& u0, const uint4& u1,
                                       const float* mu) {
    float s = 0.f;
    s = fmaf(bf2f_lo(u0.x), mu[0],  s); s = fmaf(bf2f_hi(u0.x), mu[1],  s);
    s = fmaf(bf2f_lo(u0.y), mu[2],  s); s = fmaf(bf2f_hi(u0.y), mu[3],  s);
    s = fmaf(bf2f_lo(u0.z), mu[4],  s); s = fmaf(bf2f_hi(u0.z), mu[5],  s);
    s = fmaf(bf2f_lo(u0.w), mu[6],  s); s = fmaf(bf2f_hi(u0.w), mu[7],  s);
    s = fmaf(bf2f_lo(u1.x), mu[8],  s); s = fmaf(bf2f_hi(u1.x), mu[9],  s);
    s = fmaf(bf2f_lo(u1.y), mu[10], s); s = fmaf(bf2f_hi(u1.y), mu[11], s);
    s = fmaf(bf2f_lo(u1.z), mu[12], s); s = fmaf(bf2f_hi(u1.z), mu[13], s);
    s = fmaf(bf2f_lo(u1.w), mu[14], s); s = fmaf(bf2f_hi(u1.w), mu[15], s);
    return s;
}
__device__ __forceinline__ void acc16(const uint4& u0, const uint4& u1,
                                      float e, float* acc) {
    acc[0]  = fmaf(bf2f_lo(u0.x), e, acc[0]);
    acc[1]  = fmaf(bf2f_hi(u0.x), e, acc[1]);
    acc[2]  = fmaf(bf2f_lo(u0.y), e, acc[2]);
    acc[3]  = fmaf(bf2f_hi(u0.y), e, acc[3]);
    acc[4]  = fmaf(bf2f_lo(u0.z), e, acc[4]);
    acc[5]  = fmaf(bf2f_hi(u0.z), e, acc[5]);
    acc[6]  = fmaf(bf2f_lo(u0.w), e, acc[6]);
    acc[7]  = fmaf(bf2f_hi(u0.w), e, acc[7]);
    acc[8]  = fmaf(bf2f_lo(u1.x), e, acc[8]);
    acc[9]  = fmaf(bf2f_hi(u1.x), e, acc[9]);
    acc[10] = fmaf(bf2f_lo(u1.y), e, acc[10]);
    acc[11] = fmaf(bf2f_hi(u1.y), e, acc[11]);
    acc[12] = fmaf(bf2f_lo(u1.z), e, acc[12]);
    acc[13] = fmaf(bf2f_hi(u1.z), e, acc[13]);
    acc[14] = fmaf(bf2f_lo(u1.w), e, acc[14]);
    acc[15] = fmaf(bf2f_hi(u1.w), e, acc[15]);
}

// ---------------------------------------------------------------------------
// K1: bidirectional QRNN scan (scan12 — proven 76 us). FROZEN.
// ---------------------------------------------------------------------------
__global__ __launch_bounds__(512) void qrnn_scan12(
    const float* __restrict__ x,    // (B,T,3)
    const float* __restrict__ emb,  // (V,10)
    const float* __restrict__ Wf, const float* __restrict__ bf_,
    const float* __restrict__ Wb, const float* __restrict__ bb_,
    __hip_bfloat16* __restrict__ hbuf)  // (B,T,DH)
{
    const int b = blockIdx.x, dir = blockIdx.y, h = threadIdx.x;
    const float* __restrict__ W    = dir ? Wb  : Wf;
    const float* __restrict__ bias = dir ? bb_ : bf_;

    extern __shared__ char smem[];
    float4*        tab = (float4*)smem;                       // [V][H]
    float2*        tsA = (float2*)(smem + TAB_BYTES);         // [T]
    unsigned char* vpk = (unsigned char*)(smem + TAB_BYTES + TSA_BYTES); // [T]

    {   // stage x: one thread per t
        const int t = h;
        const float* xp = x + ((size_t)b*T_ + t)*3;
        tsA[t] = make_float2(xp[0], xp[1]);
        vpk[t] = (unsigned char)(int)xp[2];
    }

    float w0[3], w1[3], wt[10][3];
#pragma unroll
    for (int g = 0; g < 3; ++g) {
        w0[g] = W[g*H_ + h];
        w1[g] = W[1536 + g*H_ + h];
#pragma unroll
        for (int e = 0; e < 10; ++e)
            wt[e][g] = W[(2+e)*1536 + g*H_ + h];
    }
    const float bz = bias[h], bfv = bias[H_+h], bov = bias[2*H_+h];

    const float FZ = -2.8853900817779268f;   // -2*log2(e)  (z gate / tanh)
    const float FF = -1.4426950408889634f;   // -log2(e)    (f,o gates)

#pragma unroll
    for (int v = 0; v < V_; ++v) {
        float a0 = bz, a1 = bfv, a2 = bov;
#pragma unroll
        for (int e = 0; e < 10; ++e) {
            const float ev = emb[v*10 + e];
            a0 = fmaf(ev, wt[e][0], a0);
            a1 = fmaf(ev, wt[e][1], a1);
            a2 = fmaf(ev, wt[e][2], a2);
        }
        tab[v*H_ + h] = make_float4(FZ*a0, FF*a1, FF*a2, 0.f);
    }
    const float w0z = FZ*w0[0], w0f = FF*w0[1], w0o = FF*w0[2];
    const float w1z = FZ*w1[0], w1f = FF*w1[1], w1o = FF*w1[2];
    __syncthreads();

    const float4* tsA4 = (const float4*)tsA;   // 2 steps per float4
    const uint2*  vp2  = (const uint2*)vpk;    // 8 steps per uint2

    float c = 0.f;
    __hip_bfloat16* hb = hbuf + (size_t)b*T_*DH_ + dir*H_ + h;   // b-major

#define SS(i, A0, A1, G) { \
    const float zp = fmaf(A0, w0z, fmaf(A1, w1z, (G).x)); \
    const float fp = fmaf(A0, w0f, fmaf(A1, w1f, (G).y)); \
    const float op = fmaf(A0, w0o, fmaf(A1, w1o, (G).z)); \
    const float rz = __builtin_amdgcn_rcpf(1.f + __builtin_amdgcn_exp2f(zp)); \
    const float f  = __builtin_amdgcn_rcpf(1.f + __builtin_amdgcn_exp2f(fp)); \
    const float o  = __builtin_amdgcn_rcpf(1.f + __builtin_amdgcn_exp2f(op)); \
    const float z  = fmaf(2.f, rz, -1.f); \
    c = fmaf(f, c - z, z); \
    const float hv = fmaxf(o * c, 0.f); \
    hb[(size_t)(t0 + (i))*DH_] = __float2bfloat16(hv); \
}

#pragma unroll 2
    for (int gi = 0; gi < T_/8; ++gi) {
        const int gg = dir ? (T_/8 - 1 - gi) : gi;
        const int t0 = gg*8;
        const uint2  vp  = vp2[gg];
        const float4 tsa = tsA4[gg*4 + 0];
        const float4 tsb = tsA4[gg*4 + 1];
        const float4 tsc = tsA4[gg*4 + 2];
        const float4 tsd = tsA4[gg*4 + 3];
        const int v0 =  vp.x        & 255, v1 = (vp.x >> 8) & 255;
        const int v2 = (vp.x >> 16) & 255, v3 =  vp.x >> 24;
        const int v4 =  vp.y        & 255, v5 = (vp.y >> 8) & 255;
        const int v6 = (vp.y >> 16) & 255, v7 =  vp.y >> 24;
        const float4 g0 = tab[v0*H_ + h];
        const float4 g1 = tab[v1*H_ + h];
        const float4 g2 = tab[v2*H_ + h];
        const float4 g3 = tab[v3*H_ + h];
        const float4 g4 = tab[v4*H_ + h];
        const float4 g5 = tab[v5*H_ + h];
        const float4 g6 = tab[v6*H_ + h];
        const float4 g7 = tab[v7*H_ + h];
        if (dir == 0) {
            SS(0, tsa.x, tsa.y, g0) SS(1, tsa.z, tsa.w, g1)
            SS(2, tsb.x, tsb.y, g2) SS(3, tsb.z, tsb.w, g3)
            SS(4, tsc.x, tsc.y, g4) SS(5, tsc.z, tsc.w, g5)
            SS(6, tsd.x, tsd.y, g6) SS(7, tsd.z, tsd.w, g7)
        } else {
            SS(7, tsd.z, tsd.w, g7) SS(6, tsd.x, tsd.y, g6)
            SS(5, tsc.z, tsc.w, g5) SS(4, tsc.x, tsc.y, g4)
            SS(3, tsb.z, tsb.w, g3) SS(2, tsb.x, tsb.y, g2)
            SS(1, tsa.z, tsa.w, g1) SS(0, tsa.x, tsa.y, g0)
        }
    }
#undef SS
}

// ---------------------------------------------------------------------------
// K2: fused epilogue, rolling 3-row window (continuous load issue, low VGPR).
// grid (NCH=8, B), block 256 (4 waves), launch_bounds(256,5) -> VGPR<=102,
// ~20 waves/CU. Wave w owns 16 consecutive rows t = q*64 + w*16 + j.
// Per row: dot -> (issue row j+3 load) -> shfl reduce -> exp -> acc.
// ---------------------------------------------------------------------------
__global__ __launch_bounds__(256, 5) void postfuse6(
    const __hip_bfloat16* __restrict__ hbuf,  // (B,T,DH)
    const float* __restrict__ Mu,             // (DH)
    float* __restrict__ pctx,                 // (B,NCH,DH) raw partial sums
    float* __restrict__ pesum)                // (B,NCH)
{
    const int q    = blockIdx.x;          // 0..NCH-1 (fastest)
    const int b    = blockIdx.y;
    const int w    = threadIdx.x >> 6;    // 0..3
    const int lane = threadIdx.x & 63;
    const int t0   = q*64 + w*16;

    __shared__ float pw[4][DH_];          // 16 KB
    __shared__ float psum[4];

    // lane's 16 Mu coefficients (d = k*512 + lane*8 + 0..7)
    float mu[16];
    {
        const float4* mp = (const float4*)Mu;
#pragma unroll
        for (int k = 0; k < 2; ++k) {
            const float4 m0 = mp[(k*64 + lane)*2];
            const float4 m1 = mp[(k*64 + lane)*2 + 1];
            mu[k*8+0]=m0.x; mu[k*8+1]=m0.y; mu[k*8+2]=m0.z; mu[k*8+3]=m0.w;
            mu[k*8+4]=m1.x; mu[k*8+5]=m1.y; mu[k*8+6]=m1.z; mu[k*8+7]=m1.w;
        }
    }

    float acc[16];
#pragma unroll
    for (int i = 0; i < 16; ++i) acc[i] = 0.f;
    float es = 0.f;

#define LOADROW(j, D0, D1) { \
    const uint4* hp = (const uint4*)(hbuf + ((size_t)b*T_ + t0 + (j))*DH_); \
    D0 = hp[lane]; D1 = hp[64 + lane]; }

#define PROCROW(C0, C1) { \
    float s = dot16(C0, C1, mu); \
    s += __shfl_xor(s, 1);  s += __shfl_xor(s, 2); \
    s += __shfl_xor(s, 4);  s += __shfl_xor(s, 8); \
    s += __shfl_xor(s, 16); s += __shfl_xor(s, 32); \
    const float e = __builtin_amdgcn_exp2f(s * LOG2E); \
    es += e; \
    acc16(C0, C1, e, acc); }

    uint4 A0, A1, B0, B1, C0, C1;
    LOADROW(0, A0, A1)
    LOADROW(1, B0, B1)
    LOADROW(2, C0, C1)

    // j=0..12: process buf, refill with row j+3 (named bufs, static schedule)
    PROCROW(A0, A1) LOADROW(3,  A0, A1)
    PROCROW(B0, B1) LOADROW(4,  B0, B1)
    PROCROW(C0, C1) LOADROW(5,  C0, C1)
    PROCROW(A0, A1) LOADROW(6,  A0, A1)
    PROCROW(B0, B1) LOADROW(7,  B0, B1)
    PROCROW(C0, C1) LOADROW(8,  C0, C1)
    PROCROW(A0, A1) LOADROW(9,  A0, A1)
    PROCROW(B0, B1) LOADROW(10, B0, B1)
    PROCROW(C0, C1) LOADROW(11, C0, C1)
    PROCROW(A0, A1) LOADROW(12, A0, A1)
    PROCROW(B0, B1) LOADROW(13, B0, B1)
    PROCROW(C0, C1) LOADROW(14, C0, C1)
    PROCROW(A0, A1) LOADROW(15, A0, A1)
    // tail: rows 13,14,15 already loaded
    PROCROW(B0, B1)
    PROCROW(C0, C1)
    PROCROW(A0, A1)

#undef LOADROW
#undef PROCROW

    // wave partials to LDS
#pragma unroll
    for (int k = 0; k < 2; ++k) {
        *(float4*)&pw[w][k*512 + lane*8]     = make_float4(acc[k*8+0], acc[k*8+1], acc[k*8+2], acc[k*8+3]);
        *(float4*)&pw[w][k*512 + lane*8 + 4] = make_float4(acc[k*8+4], acc[k*8+5], acc[k*8+6], acc[k*8+7]);
    }
    if (lane == 0) psum[w] = es;
    __syncthreads();

    // combine 4 wave partials; thread covers d = k*256 + tid
    float* pc = pctx + ((size_t)b*NCH + q)*DH_;
#pragma unroll
    for (int k = 0; k < 4; ++k) {
        const int d = k*256 + threadIdx.x;
        pc[d] = pw[0][d] + pw[1][d] + pw[2][d] + pw[3][d];
    }
    if (threadIdx.x == 0)
        pesum[b*NCH + q] = psum[0] + psum[1] + psum[2] + psum[3];
}

// ---------------------------------------------------------------------------
// K3: combine partials -> relu -> normalized output GEMV. grid B, block 512.
// ---------------------------------------------------------------------------
__global__ __launch_bounds__(512) void combine_out(
    const float* __restrict__ pctx,   // (B,NCH,DH)
    const float* __restrict__ pesum,  // (B,NCH)
    const float* __restrict__ Wout,   // (OUT,DH)
    const float* __restrict__ bout,   // (OUT)
    float* __restrict__ out)          // (B,OUT)
{
    const int b    = blockIdx.x;
    const int w    = threadIdx.x >> 6;    // 0..7
    const int lane = threadIdx.x & 63;

    __shared__ float ctx[DH_];
    __shared__ float rinv_s;

    {
        const int d = threadIdx.x;
        const float* pc = pctx + (size_t)b*NCH*DH_;
        float c0 = 0.f, c1 = 0.f;
#pragma unroll
        for (int i = 0; i < NCH; ++i) { c0 += pc[i*DH_ + d]; c1 += pc[i*DH_ + d + 512]; }
        ctx[d]       = fmaxf(c0, 0.f);
        ctx[d + 512] = fmaxf(c1, 0.f);
    }
    if (threadIdx.x == 0) {
        float ts = 0.f;
#pragma unroll
        for (int i = 0; i < NCH; ++i) ts += pesum[b*NCH + i];
        rinv_s = __builtin_amdgcn_rcpf(ts);
    }
    __syncthreads();

    const float rinv = rinv_s;
#pragma unroll
    for (int oo = 0; oo < 8; ++oo) {
        const int o = w*8 + oo;
        const float* wp = Wout + o*DH_;
        float a = 0.f;
#pragma unroll
        for (int k = 0; k < 16; ++k) {
            const int d = k*64 + lane;
            a = fmaf(ctx[d], wp[d], a);
        }
#pragma unroll
        for (int off = 1; off <= 32; off <<= 1) a += __shfl_xor(a, off);
        if (lane == 0) out[b*OUT_ + o] = a*rinv + bout[o];
    }
}

// ---------------------------------------------------------------------------
extern "C" void kernel_launch(void* const* d_in, const int* in_sizes, int n_in,
                              void* d_out, int out_size, void* d_ws, size_t ws_size,
                              hipStream_t stream)
{
    const float* x    = (const float*)d_in[0];
    const float* emb  = (const float*)d_in[1];
    const float* Wf   = (const float*)d_in[2];
    const float* bf_  = (const float*)d_in[3];
    const float* Wb   = (const float*)d_in[4];
    const float* bb_  = (const float*)d_in[5];
    const float* Mu   = (const float*)d_in[6];
    const float* Wout = (const float*)d_in[7];
    const float* bout = (const float*)d_in[8];
    float* out = (float*)d_out;

    char* ws = (char*)d_ws;
    const size_t hbytes = (size_t)B_*T_*DH_*sizeof(__hip_bfloat16);  // 134.2 MB
    __hip_bfloat16* hbuf = (__hip_bfloat16*)ws;         // [B][T][DH]
    float* pctx  = (float*)(ws + hbytes);               // B*NCH*DH (4 MB)
    float* pesum = pctx + (size_t)B_*NCH*DH_;           // B*NCH

    (void)hipFuncSetAttribute((const void*)qrnn_scan12,
                              hipFuncAttributeMaxDynamicSharedMemorySize,
                              SCAN_LDS);

    qrnn_scan12<<<dim3(B_, 2), 512, SCAN_LDS, stream>>>(x, emb, Wf, bf_, Wb, bb_, hbuf);
    postfuse6<<<dim3(NCH, B_), 256, 0, stream>>>(hbuf, Mu, pctx, pesum);
    combine_out<<<B_, 512, 0, stream>>>(pctx, pesum, Wout, bout, out);
}

// Round 14
// 168.225 us; speedup vs baseline: 1.7574x; 1.7574x over previous
//
#include <hip/hip_runtime.h>
#include <hip/hip_bf16.h>

#define B_   128
#define T_   512
#define H_   512
#define V_   16
#define OUT_ 64
#define DH_  1024
#define NCH  8     // t-chunks per batch for the fused epilogue

// hbuf layout: [b][T_][DH_]  (b-major)

// scan LDS: tab float4[V][H] (128K) + tsA float2[T] (4K) + vpk uchar[T] (512B)
#define TAB_BYTES (V_*H_*16)
#define TSA_BYTES (T_*8)
#define VPK_BYTES (T_)
#define SCAN_LDS  (TAB_BYTES + TSA_BYTES + VPK_BYTES)   // 135,680 B

#define LOG2E 1.4426950408889634f

__device__ __forceinline__ float bf2f_lo(unsigned int u) {
    union { unsigned int i; float f; } x; x.i = u << 16; return x.f;
}
__device__ __forceinline__ float bf2f_hi(unsigned int u) {
    union { unsigned int i; float f; } x; x.i = u & 0xffff0000u; return x.f;
}

__device__ __forceinline__ float dot16(const uint4& u0, const uint4& u1,
                                       const float* mu) {
    float s = 0.f;
    s = fmaf(bf2f_lo(u0.x), mu[0],  s); s = fmaf(bf2f_hi(u0.x), mu[1],  s);
    s = fmaf(bf2f_lo(u0.y), mu[2],  s); s = fmaf(bf2f_hi(u0.y), mu[3],  s);
    s = fmaf(bf2f_lo(u0.z), mu[4],  s); s = fmaf(bf2f_hi(u0.z), mu[5],  s);
    s = fmaf(bf2f_lo(u0.w), mu[6],  s); s = fmaf(bf2f_hi(u0.w), mu[7],  s);
    s = fmaf(bf2f_lo(u1.x), mu[8],  s); s = fmaf(bf2f_hi(u1.x), mu[9],  s);
    s = fmaf(bf2f_lo(u1.y), mu[10], s); s = fmaf(bf2f_hi(u1.y), mu[11], s);
    s = fmaf(bf2f_lo(u1.z), mu[12], s); s = fmaf(bf2f_hi(u1.z), mu[13], s);
    s = fmaf(bf2f_lo(u1.w), mu[14], s); s = fmaf(bf2f_hi(u1.w), mu[15], s);
    return s;
}
__device__ __forceinline__ void acc16(const uint4& u0, const uint4& u1,
                                      float e, float* acc) {
    acc[0]  = fmaf(bf2f_lo(u0.x), e, acc[0]);
    acc[1]  = fmaf(bf2f_hi(u0.x), e, acc[1]);
    acc[2]  = fmaf(bf2f_lo(u0.y), e, acc[2]);
    acc[3]  = fmaf(bf2f_hi(u0.y), e, acc[3]);
    acc[4]  = fmaf(bf2f_lo(u0.z), e, acc[4]);
    acc[5]  = fmaf(bf2f_hi(u0.z), e, acc[5]);
    acc[6]  = fmaf(bf2f_lo(u0.w), e, acc[6]);
    acc[7]  = fmaf(bf2f_hi(u0.w), e, acc[7]);
    acc[8]  = fmaf(bf2f_lo(u1.x), e, acc[8]);
    acc[9]  = fmaf(bf2f_hi(u1.x), e, acc[9]);
    acc[10] = fmaf(bf2f_lo(u1.y), e, acc[10]);
    acc[11] = fmaf(bf2f_hi(u1.y), e, acc[11]);
    acc[12] = fmaf(bf2f_lo(u1.z), e, acc[12]);
    acc[13] = fmaf(bf2f_hi(u1.z), e, acc[13]);
    acc[14] = fmaf(bf2f_lo(u1.w), e, acc[14]);
    acc[15] = fmaf(bf2f_hi(u1.w), e, acc[15]);
}

// ---------------------------------------------------------------------------
// K1: bidirectional QRNN scan (scan12 — proven 76 us). FROZEN.
// ---------------------------------------------------------------------------
__global__ __launch_bounds__(512) void qrnn_scan12(
    const float* __restrict__ x,    // (B,T,3)
    const float* __restrict__ emb,  // (V,10)
    const float* __restrict__ Wf, const float* __restrict__ bf_,
    const float* __restrict__ Wb, const float* __restrict__ bb_,
    __hip_bfloat16* __restrict__ hbuf)  // (B,T,DH)
{
    const int b = blockIdx.x, dir = blockIdx.y, h = threadIdx.x;
    const float* __restrict__ W    = dir ? Wb  : Wf;
    const float* __restrict__ bias = dir ? bb_ : bf_;

    extern __shared__ char smem[];
    float4*        tab = (float4*)smem;                       // [V][H]
    float2*        tsA = (float2*)(smem + TAB_BYTES);         // [T]
    unsigned char* vpk = (unsigned char*)(smem + TAB_BYTES + TSA_BYTES); // [T]

    {   // stage x: one thread per t
        const int t = h;
        const float* xp = x + ((size_t)b*T_ + t)*3;
        tsA[t] = make_float2(xp[0], xp[1]);
        vpk[t] = (unsigned char)(int)xp[2];
    }

    float w0[3], w1[3], wt[10][3];
#pragma unroll
    for (int g = 0; g < 3; ++g) {
        w0[g] = W[g*H_ + h];
        w1[g] = W[1536 + g*H_ + h];
#pragma unroll
        for (int e = 0; e < 10; ++e)
            wt[e][g] = W[(2+e)*1536 + g*H_ + h];
    }
    const float bz = bias[h], bfv = bias[H_+h], bov = bias[2*H_+h];

    const float FZ = -2.8853900817779268f;   // -2*log2(e)  (z gate / tanh)
    const float FF = -1.4426950408889634f;   // -log2(e)    (f,o gates)

#pragma unroll
    for (int v = 0; v < V_; ++v) {
        float a0 = bz, a1 = bfv, a2 = bov;
#pragma unroll
        for (int e = 0; e < 10; ++e) {
            const float ev = emb[v*10 + e];
            a0 = fmaf(ev, wt[e][0], a0);
            a1 = fmaf(ev, wt[e][1], a1);
            a2 = fmaf(ev, wt[e][2], a2);
        }
        tab[v*H_ + h] = make_float4(FZ*a0, FF*a1, FF*a2, 0.f);
    }
    const float w0z = FZ*w0[0], w0f = FF*w0[1], w0o = FF*w0[2];
    const float w1z = FZ*w1[0], w1f = FF*w1[1], w1o = FF*w1[2];
    __syncthreads();

    const float4* tsA4 = (const float4*)tsA;   // 2 steps per float4
    const uint2*  vp2  = (const uint2*)vpk;    // 8 steps per uint2

    float c = 0.f;
    __hip_bfloat16* hb = hbuf + (size_t)b*T_*DH_ + dir*H_ + h;   // b-major

#define SS(i, A0, A1, G) { \
    const float zp = fmaf(A0, w0z, fmaf(A1, w1z, (G).x)); \
    const float fp = fmaf(A0, w0f, fmaf(A1, w1f, (G).y)); \
    const float op = fmaf(A0, w0o, fmaf(A1, w1o, (G).z)); \
    const float rz = __builtin_amdgcn_rcpf(1.f + __builtin_amdgcn_exp2f(zp)); \
    const float f  = __builtin_amdgcn_rcpf(1.f + __builtin_amdgcn_exp2f(fp)); \
    const float o  = __builtin_amdgcn_rcpf(1.f + __builtin_amdgcn_exp2f(op)); \
    const float z  = fmaf(2.f, rz, -1.f); \
    c = fmaf(f, c - z, z); \
    const float hv = fmaxf(o * c, 0.f); \
    hb[(size_t)(t0 + (i))*DH_] = __float2bfloat16(hv); \
}

#pragma unroll 2
    for (int gi = 0; gi < T_/8; ++gi) {
        const int gg = dir ? (T_/8 - 1 - gi) : gi;
        const int t0 = gg*8;
        const uint2  vp  = vp2[gg];
        const float4 tsa = tsA4[gg*4 + 0];
        const float4 tsb = tsA4[gg*4 + 1];
        const float4 tsc = tsA4[gg*4 + 2];
        const float4 tsd = tsA4[gg*4 + 3];
        const int v0 =  vp.x        & 255, v1 = (vp.x >> 8) & 255;
        const int v2 = (vp.x >> 16) & 255, v3 =  vp.x >> 24;
        const int v4 =  vp.y        & 255, v5 = (vp.y >> 8) & 255;
        const int v6 = (vp.y >> 16) & 255, v7 =  vp.y >> 24;
        const float4 g0 = tab[v0*H_ + h];
        const float4 g1 = tab[v1*H_ + h];
        const float4 g2 = tab[v2*H_ + h];
        const float4 g3 = tab[v3*H_ + h];
        const float4 g4 = tab[v4*H_ + h];
        const float4 g5 = tab[v5*H_ + h];
        const float4 g6 = tab[v6*H_ + h];
        const float4 g7 = tab[v7*H_ + h];
        if (dir == 0) {
            SS(0, tsa.x, tsa.y, g0) SS(1, tsa.z, tsa.w, g1)
            SS(2, tsb.x, tsb.y, g2) SS(3, tsb.z, tsb.w, g3)
            SS(4, tsc.x, tsc.y, g4) SS(5, tsc.z, tsc.w, g5)
            SS(6, tsd.x, tsd.y, g6) SS(7, tsd.z, tsd.w, g7)
        } else {
            SS(7, tsd.z, tsd.w, g7) SS(6, tsd.x, tsd.y, g6)
            SS(5, tsc.z, tsc.w, g5) SS(4, tsc.x, tsc.y, g4)
            SS(3, tsb.z, tsb.w, g3) SS(2, tsb.x, tsb.y, g2)
            SS(1, tsa.z, tsa.w, g1) SS(0, tsa.x, tsa.y, g0)
        }
    }
#undef SS
}

// ---------------------------------------------------------------------------
// K2: fused epilogue, rolling 3-row window — round-13 structure with the
// VGPR clamp REMOVED (the (256,5) bound caused 370 MB of scratch spill;
// unclamped needs ~85 VGPR, no spill, still ~5 waves/SIMD).
// ---------------------------------------------------------------------------
__global__ __launch_bounds__(256) void postfuse6b(
    const __hip_bfloat16* __restrict__ hbuf,  // (B,T,DH)
    const float* __restrict__ Mu,             // (DH)
    float* __restrict__ pctx,                 // (B,NCH,DH) raw partial sums
    float* __restrict__ pesum)                // (B,NCH)
{
    const int q    = blockIdx.x;          // 0..NCH-1 (fastest)
    const int b    = blockIdx.y;
    const int w    = threadIdx.x >> 6;    // 0..3
    const int lane = threadIdx.x & 63;
    const int t0   = q*64 + w*16;

    __shared__ float pw[4][DH_];          // 16 KB
    __shared__ float psum[4];

    // lane's 16 Mu coefficients (d = k*512 + lane*8 + 0..7)
    float mu[16];
    {
        const float4* mp = (const float4*)Mu;
#pragma unroll
        for (int k = 0; k < 2; ++k) {
            const float4 m0 = mp[(k*64 + lane)*2];
            const float4 m1 = mp[(k*64 + lane)*2 + 1];
            mu[k*8+0]=m0.x; mu[k*8+1]=m0.y; mu[k*8+2]=m0.z; mu[k*8+3]=m0.w;
            mu[k*8+4]=m1.x; mu[k*8+5]=m1.y; mu[k*8+6]=m1.z; mu[k*8+7]=m1.w;
        }
    }

    float acc[16];
#pragma unroll
    for (int i = 0; i < 16; ++i) acc[i] = 0.f;
    float es = 0.f;

#define LOADROW(j, D0, D1) { \
    const uint4* hp = (const uint4*)(hbuf + ((size_t)b*T_ + t0 + (j))*DH_); \
    D0 = hp[lane]; D1 = hp[64 + lane]; }

#define PROCROW(C0, C1) { \
    float s = dot16(C0, C1, mu); \
    s += __shfl_xor(s, 1);  s += __shfl_xor(s, 2); \
    s += __shfl_xor(s, 4);  s += __shfl_xor(s, 8); \
    s += __shfl_xor(s, 16); s += __shfl_xor(s, 32); \
    const float e = __builtin_amdgcn_exp2f(s * LOG2E); \
    es += e; \
    acc16(C0, C1, e, acc); }

    uint4 A0, A1, B0, B1, C0, C1;
    LOADROW(0, A0, A1)
    LOADROW(1, B0, B1)
    LOADROW(2, C0, C1)

    PROCROW(A0, A1) LOADROW(3,  A0, A1)
    PROCROW(B0, B1) LOADROW(4,  B0, B1)
    PROCROW(C0, C1) LOADROW(5,  C0, C1)
    PROCROW(A0, A1) LOADROW(6,  A0, A1)
    PROCROW(B0, B1) LOADROW(7,  B0, B1)
    PROCROW(C0, C1) LOADROW(8,  C0, C1)
    PROCROW(A0, A1) LOADROW(9,  A0, A1)
    PROCROW(B0, B1) LOADROW(10, B0, B1)
    PROCROW(C0, C1) LOADROW(11, C0, C1)
    PROCROW(A0, A1) LOADROW(12, A0, A1)
    PROCROW(B0, B1) LOADROW(13, B0, B1)
    PROCROW(C0, C1) LOADROW(14, C0, C1)
    PROCROW(A0, A1) LOADROW(15, A0, A1)
    PROCROW(B0, B1)
    PROCROW(C0, C1)
    PROCROW(A0, A1)

#undef LOADROW
#undef PROCROW

    // wave partials to LDS
#pragma unroll
    for (int k = 0; k < 2; ++k) {
        *(float4*)&pw[w][k*512 + lane*8]     = make_float4(acc[k*8+0], acc[k*8+1], acc[k*8+2], acc[k*8+3]);
        *(float4*)&pw[w][k*512 + lane*8 + 4] = make_float4(acc[k*8+4], acc[k*8+5], acc[k*8+6], acc[k*8+7]);
    }
    if (lane == 0) psum[w] = es;
    __syncthreads();

    // combine 4 wave partials; thread covers d = k*256 + tid
    float* pc = pctx + ((size_t)b*NCH + q)*DH_;
#pragma unroll
    for (int k = 0; k < 4; ++k) {
        const int d = k*256 + threadIdx.x;
        pc[d] = pw[0][d] + pw[1][d] + pw[2][d] + pw[3][d];
    }
    if (threadIdx.x == 0)
        pesum[b*NCH + q] = psum[0] + psum[1] + psum[2] + psum[3];
}

// ---------------------------------------------------------------------------
// K3: combine partials -> relu -> normalized output GEMV. grid B, block 512.
// ---------------------------------------------------------------------------
__global__ __launch_bounds__(512) void combine_out(
    const float* __restrict__ pctx,   // (B,NCH,DH)
    const float* __restrict__ pesum,  // (B,NCH)
    const float* __restrict__ Wout,   // (OUT,DH)
    const float* __restrict__ bout,   // (OUT)
    float* __restrict__ out)          // (B,OUT)
{
    const int b    = blockIdx.x;
    const int w    = threadIdx.x >> 6;    // 0..7
    const int lane = threadIdx.x & 63;

    __shared__ float ctx[DH_];
    __shared__ float rinv_s;

    {
        const int d = threadIdx.x;
        const float* pc = pctx + (size_t)b*NCH*DH_;
        float c0 = 0.f, c1 = 0.f;
#pragma unroll
        for (int i = 0; i < NCH; ++i) { c0 += pc[i*DH_ + d]; c1 += pc[i*DH_ + d + 512]; }
        ctx[d]       = fmaxf(c0, 0.f);
        ctx[d + 512] = fmaxf(c1, 0.f);
    }
    if (threadIdx.x == 0) {
        float ts = 0.f;
#pragma unroll
        for (int i = 0; i < NCH; ++i) ts += pesum[b*NCH + i];
        rinv_s = __builtin_amdgcn_rcpf(ts);
    }
    __syncthreads();

    const float rinv = rinv_s;
#pragma unroll
    for (int oo = 0; oo < 8; ++oo) {
        const int o = w*8 + oo;
        const float* wp = Wout + o*DH_;
        float a = 0.f;
#pragma unroll
        for (int k = 0; k < 16; ++k) {
            const int d = k*64 + lane;
            a = fmaf(ctx[d], wp[d], a);
        }
#pragma unroll
        for (int off = 1; off <= 32; off <<= 1) a += __shfl_xor(a, off);
        if (lane == 0) out[b*OUT_ + o] = a*rinv + bout[o];
    }
}

// ---------------------------------------------------------------------------
extern "C" void kernel_launch(void* const* d_in, const int* in_sizes, int n_in,
                              void* d_out, int out_size, void* d_ws, size_t ws_size,
                              hipStream_t stream)
{
    const float* x    = (const float*)d_in[0];
    const float* emb  = (const float*)d_in[1];
    const float* Wf   = (const float*)d_in[2];
    const float* bf_  = (const float*)d_in[3];
    const float* Wb   = (const float*)d_in[4];
    const float* bb_  = (const float*)d_in[5];
    const float* Mu   = (const float*)d_in[6];
    const float* Wout = (const float*)d_in[7];
    const float* bout = (const float*)d_in[8];
    float* out = (float*)d_out;

    char* ws = (char*)d_ws;
    const size_t hbytes = (size_t)B_*T_*DH_*sizeof(__hip_bfloat16);  // 134.2 MB
    __hip_bfloat16* hbuf = (__hip_bfloat16*)ws;         // [B][T][DH]
    float* pctx  = (float*)(ws + hbytes);               // B*NCH*DH (4 MB)
    float* pesum = pctx + (size_t)B_*NCH*DH_;           // B*NCH

    (void)hipFuncSetAttribute((const void*)qrnn_scan12,
                              hipFuncAttributeMaxDynamicSharedMemorySize,
                              SCAN_LDS);

    qrnn_scan12<<<dim3(B_, 2), 512, SCAN_LDS, stream>>>(x, emb, Wf, bf_, Wb, bb_, hbuf);
    postfuse6b<<<dim3(NCH, B_), 256, 0, stream>>>(hbuf, Mu, pctx, pesum);
    combine_out<<<B_, 512, 0, stream>>>(pctx, pesum, Wout, bout, out);
}